// Round 10
// baseline (78.759 us; speedup 1.0000x reference)
//
#include <hip/hip_runtime.h>
#include <hip/hip_bf16.h>
#include <stdint.h>

#define HH 128
#define WW 128
#define HWPX 16384
#define BIGL 16384
#define NT 1024
#define INFI 0x7FFFFFFF

// ---- UF primitives (R4/R7-validated) ----
__device__ __forceinline__ int findRootH(int* L, int x) {   // during unions
    int p = L[x];
    while (p != x) {
        int g = L[p];
        if (g != p) atomicMin(&L[x], g);
        x = p; p = g;
    }
    return x;
}
__device__ __forceinline__ int findRootF(int* L, int x) {   // post-union, plain halving
    int p = L[x];
    while (p != x) {
        int g = L[p];
        if (g != p) L[x] = g;
        x = p; p = g;
    }
    return p;
}
// masked find: low 16 bits = parent, high bits may hold area on roots.
// Plain halving stores only to non-roots (high bits 0 there).
__device__ __forceinline__ int findRootM(int* L, int x) {
    int p = L[x] & 0xFFFF;
    while (p != x) {
        int g = L[p] & 0xFFFF;
        if (g != p) L[x] = g;
        x = p; p = g;
    }
    return p;
}
__device__ __forceinline__ void uni(int* L, int a, int b) {
    a = findRootH(L, a);
    b = findRootH(L, b);
    while (a != b) {
        if (a > b) { int t = a; a = b; b = t; }
        int old = atomicMin(&L[b], a);
        if (old == b) break;
        b = findRootH(L, old);
    }
}

__device__ __forceinline__ int wsumi(int v)    { for (int o = 32; o; o >>= 1) v += __shfl_xor(v, o, 64); return v; }
__device__ __forceinline__ float wsumf(float v){ for (int o = 32; o; o >>= 1) v += __shfl_xor(v, o, 64); return v; }
__device__ __forceinline__ int wmini(int v)    { for (int o = 32; o; o >>= 1) v = min(v, __shfl_xor(v, o, 64)); return v; }
__device__ __forceinline__ int wmaxi(int v)    { for (int o = 32; o; o >>= 1) v = max(v, __shfl_xor(v, o, 64)); return v; }

// =============== K1: per-strip CCL (nmask*8 blocks, 16 rows / 2048 px each) ===============
// Outputs: per-pixel root label (u16, 0xFFFF=bg, value = strip*2048+localroot),
// compact records (area<<16|localroot) + counts, per-strip sum.
__global__ __launch_bounds__(NT)
void cc_strip_kernel(const float* __restrict__ masks, unsigned* __restrict__ labs32,
                     unsigned* __restrict__ recs, int* __restrict__ counts,
                     float* __restrict__ sums) {
    __shared__ int L[2048];                  // 8 KB UF parents; roots get area<<16
    __shared__ unsigned long long rb0[16], rb1[16];  // per-row ballots (even/odd cols)
    __shared__ float s_wsum[16];
    __shared__ int s_cnt;

    const int tid  = threadIdx.x;
    const int lane = tid & 63;
    const int wv   = tid >> 6;               // wave == local row (64 lanes * 2px = 128 cols)
    const int strip = blockIdx.x;
    const int im = strip >> 3, s = strip & 7;
    const float* msk = masks + ((size_t)im << 14) + (s << 11);
    const int i0 = tid * 2;                  // local flat index of px0

    float2 v = ((const float2*)(msk + i0))[0];
    unsigned fg = (v.x > 0.f ? 1u : 0u) | (v.y > 0.f ? 2u : 0u);
    float tsum = v.x + v.y;

    // chunk-local run-head labels (bg = identity, never chased)
    int lab1 = (fg & 2) ? ((fg & 1) ? i0 : i0 + 1) : (i0 + 1);
    ((int2*)(L + i0))[0] = make_int2(i0, lab1);

    unsigned long long b0 = __ballot(fg & 1);   // fg of even cols (px0 per lane)
    unsigned long long b1 = __ballot(fg & 2);   // fg of odd cols  (px1 per lane)
    if (lane == 0) { rb0[wv] = b0; rb1[wv] = b1; }
    const unsigned leftbit  = (lane > 0)  ? (unsigned)((b1 >> (lane - 1)) & 1) : 0u;
    const unsigned rightbit = (lane < 63) ? (unsigned)((b0 >> (lane + 1)) & 1) : 0u;

    tsum = wsumf(tsum);
    if (lane == 0) s_wsum[wv] = tsum;
    if (tid == 0) s_cnt = 0;
    __syncthreads();

    if (tid < 64) {       // block sum -> sums[strip]
        float t = (tid < 16) ? s_wsum[tid] : 0.f;
        for (int o = 8; o; o >>= 1) t += __shfl_xor(t, o, 64);
        if (tid == 0) sums[strip] = t;
    }

    // merge: horizontal stitch + dedup'd vertical unions (straight-line, 2 px)
    if ((fg & 1) && leftbit) uni(L, i0, i0 - 1);
    if (fg && wv > 0) {
        unsigned long long u0 = rb0[wv - 1], u1 = rb1[wv - 1];
        unsigned UP0 = (unsigned)((u0 >> lane) & 1);
        unsigned UR0 = (unsigned)((u1 >> lane) & 1);
        unsigned UL0 = (lane > 0)  ? (unsigned)((u1 >> (lane - 1)) & 1) : 0u;
        unsigned UR1 = (lane < 63) ? (unsigned)((u0 >> (lane + 1)) & 1) : 0u;
        if (fg & 1) {                        // px0: UL=UL0 UP=UP0 UR=UR0, lF=leftbit, rF=fg&2
            if (!leftbit) {
                if (UL0)         uni(L, i0, i0 - 129);
                if (UP0 && !UL0) uni(L, i0, i0 - 128);
                if (UR0 && !UP0) uni(L, i0, i0 - 127);
            } else {
                if (UP0 && !UL0)              uni(L, i0, i0 - 128);
                if (!(fg & 2) && UR0 && !UP0) uni(L, i0, i0 - 127);
            }
        }
        if (fg & 2) {                        // px1: UL=UP0 UP=UR0 UR=UR1, lF=fg&1, rF=rightbit
            if (!(fg & 1)) {
                if (UP0)         uni(L, i0 + 1, i0 - 128);
                if (UR0 && !UP0) uni(L, i0 + 1, i0 - 127);
                if (UR1 && !UR0) uni(L, i0 + 1, i0 - 126);
            } else {
                if (UR0 && !UP0)              uni(L, i0 + 1, i0 - 127);
                if (!rightbit && UR1 && !UR0) uni(L, i0 + 1, i0 - 126);
            }
        }
    }
    __syncthreads();

    // flatten: one find per chunk-local run, compress heads
    int rr0 = -1, rr1 = -1;
    if (fg & 1) { rr0 = findRootF(L, i0); L[i0] = rr0; }
    if (fg & 2) {
        if (fg & 1) rr1 = rr0;
        else { rr1 = findRootF(L, i0 + 1); L[i0 + 1] = rr1; }
    }
    int fr = (rr0 >= 0) ? rr0 : ((rr1 >= 0) ? rr1 : INFI);
    __syncthreads();

    // areas into high bits (wave-aggregated dominant root)
    {
        const int R0 = wmini(fr);
        int giant = 0;
        if (fg == 3u) {                      // same run, same root
            if (rr0 == R0) giant = 2; else atomicAdd(&L[rr0], 2 << 16);
        } else {
            if (fg & 1) { if (rr0 == R0) ++giant; else atomicAdd(&L[rr0], 1 << 16); }
            if (fg & 2) { if (rr1 == R0) ++giant; else atomicAdd(&L[rr1], 1 << 16); }
        }
        int g = wsumi(giant);
        if (lane == 0 && R0 != INFI && g) atomicAdd(&L[R0], g << 16);
    }
    __syncthreads();

    // records (roots among chunk heads) + per-pixel label output
    if (fg & 1) {
        int e = L[i0];
        if ((e & 0xFFFF) == i0 && (e >> 16)) {
            int x = atomicAdd(&s_cnt, 1);
            recs[(strip << 9) + x] = ((unsigned)e & 0xFFFF0000u) | (unsigned)i0;
        }
    }
    if (fg == 2u) {
        int e = L[i0 + 1];
        if ((e & 0xFFFF) == (i0 + 1) && (e >> 16)) {
            int x = atomicAdd(&s_cnt, 1);
            recs[(strip << 9) + x] = ((unsigned)e & 0xFFFF0000u) | (unsigned)(i0 + 1);
        }
    }
    {
        unsigned lo = (fg & 1) ? (unsigned)((s << 11) + rr0) : 0xFFFFu;
        unsigned hi = (fg & 2) ? (unsigned)((s << 11) + rr1) : 0xFFFFu;
        labs32[((size_t)im << 13) + (s << 10) + tid] = lo | (hi << 16);
    }
    __syncthreads();
    if (tid == 0) counts[strip] = s_cnt;
}

// =============== K2: per-image label-space merge + stats (nmask blocks) ===============
__global__ __launch_bounds__(NT)
void cc_stats2(const float* __restrict__ masks, const unsigned* __restrict__ labs32,
               const unsigned* __restrict__ recs, const int* __restrict__ counts,
               const float* __restrict__ sums, float* __restrict__ losses) {
    __shared__ int L[HWPX];                  // 64 KB label-space UF; roots get area<<16
    __shared__ unsigned s_wk[32];
    __shared__ int s_wi[16];
    __shared__ float s_wsum[16];
    __shared__ int s_cnt8[8];
    __shared__ int s_r0, s_r1, s_c0, s_c1;
    __shared__ unsigned s_k2;
    __shared__ float s_total;

    const int tid  = threadIdx.x;
    const int lane = tid & 63;
    const int wid  = tid >> 6;
    const int im   = blockIdx.x;
    const int row  = tid >> 3;               // 16 px/thread, 8 threads/row
    const int col0 = (tid & 7) * 16;

    // per-pixel labels (16 u16 = two uint4)
    const uint4* lp = (const uint4*)(labs32 + ((size_t)im << 13));
    uint4 A = lp[tid * 2], B = lp[tid * 2 + 1];
    int lb[16];
    lb[0]=A.x&0xFFFF; lb[1]=A.x>>16; lb[2]=A.y&0xFFFF; lb[3]=A.y>>16;
    lb[4]=A.z&0xFFFF; lb[5]=A.z>>16; lb[6]=A.w&0xFFFF; lb[7]=A.w>>16;
    lb[8]=B.x&0xFFFF; lb[9]=B.x>>16; lb[10]=B.y&0xFFFF; lb[11]=B.y>>16;
    lb[12]=B.z&0xFFFF; lb[13]=B.z>>16; lb[14]=B.w&0xFFFF; lb[15]=B.w>>16;
    unsigned fgbits = 0;
#pragma unroll
    for (int k = 0; k < 16; ++k) fgbits |= (lb[k] != 0xFFFF) ? (1u << k) : 0u;

    // L init = identity
    {
        int b16 = tid * 16;
        int4* Lv = (int4*)(L + b16);
#pragma unroll
        for (int q = 0; q < 4; ++q)
            Lv[q] = make_int4(b16 + q*4, b16 + q*4 + 1, b16 + q*4 + 2, b16 + q*4 + 3);
    }
    if (tid < 8) s_cnt8[tid] = counts[im * 8 + tid];
    if (tid == 0) {
        s_r0 = HH; s_r1 = -1; s_c0 = WW; s_c1 = -1;
        float t = 0.f;
        for (int q = 0; q < 8; ++q) t += sums[im * 8 + q];
        s_total = t;
    }
    __syncthreads();

    // seam unions (rows 16,32,...,112 against row-1), label-space, dedup'd events
    if (row > 0 && (row & 15) == 0 && fgbits) {
        const unsigned short* labsu = (const unsigned short*)(labs32 + ((size_t)im << 13));
        int up[18];
        unsigned upb = 0;
#pragma unroll
        for (int d = 0; d < 18; ++d) {
            int c = col0 + d - 1;
            int lv = (c >= 0 && c < WW) ? (int)labsu[(row - 1) * WW + c] : 0xFFFF;
            up[d] = lv;
            upb |= (lv != 0xFFFF) ? (1u << d) : 0u;
        }
        unsigned leftb  = (col0 > 0)   ? (labsu[row * WW + col0 - 1]  != 0xFFFF) : 0u;
        unsigned rightb = (col0 < 112) ? (labsu[row * WW + col0 + 16] != 0xFFFF) : 0u;
        const unsigned ULv = upb & 0xFFFFu;
        const unsigned UPv = (upb >> 1) & 0xFFFFu;
        const unsigned URv = (upb >> 2) & 0xFFFFu;
        const unsigned lFv = ((fgbits << 1) | leftb) & 0xFFFFu;
        const unsigned rFv = (fgbits >> 1) | (rightb << 15);
        unsigned m = fgbits & ( (~lFv & (ULv | UPv | URv))
                              | (lFv & ((UPv & ~ULv) | (~rFv & URv & ~UPv))) );
        while (m) {
            int k = __ffs(m) - 1; m &= m - 1;
            unsigned UL = (ULv >> k) & 1u, UP = (UPv >> k) & 1u, UR = (URv >> k) & 1u;
            unsigned lF = (lFv >> k) & 1u, rF = (rFv >> k) & 1u;
            if (!lF) {
                if (UL)        uni(L, lb[k], up[k]);
                if (UP && !UL) uni(L, lb[k], up[k + 1]);
                if (UR && !UP) uni(L, lb[k], up[k + 2]);
            } else {
                if (UP && !UL)        uni(L, lb[k], up[k + 1]);
                if (!rF && UR && !UP) uni(L, lb[k], up[k + 2]);
            }
        }
    }
    __syncthreads();

    // record pass: compress record labels to class roots, accumulate areas
    for (int s = 0; s < 8; ++s) {
        int c = s_cnt8[s];
        for (int i = tid; i < c; i += NT) {
            unsigned rec = recs[((im * 8 + s) << 9) + i];
            int lab = (s << 11) + (int)(rec & 0xFFFFu);
            int r = findRootM(L, lab);
            if (lab != r) L[lab] = r;
            atomicAdd(&L[r], (int)(rec >> 16) << 16);
        }
    }
    __syncthreads();

    // top-2 over class roots (+ background), key = area<<15 | (BIGL - label)
    unsigned b1 = 0, b2 = 0;
    int fgsum = 0;
    for (int s = 0; s < 8; ++s) {
        int c = s_cnt8[s];
        for (int i = tid; i < c; i += NT) {
            unsigned rec = recs[((im * 8 + s) << 9) + i];
            int lab = (s << 11) + (int)(rec & 0xFFFFu);
            fgsum += (int)(rec >> 16);
            int e = L[lab];
            if ((e & 0xFFFF) == lab && (e >> 16)) {
                unsigned key = ((unsigned)(e >> 16) << 15) | (unsigned)(BIGL - lab);
                if (key > b1) { b2 = b1; b1 = key; }
                else if (key > b2) b2 = key;
            }
        }
    }
    for (int o = 32; o; o >>= 1) {
        unsigned p1 = __shfl_xor(b1, o, 64);
        unsigned p2 = __shfl_xor(b2, o, 64);
        if (p1 > b1) { b2 = (b1 > p2 ? b1 : p2); b1 = p1; }
        else if (p1 > b2) b2 = p1;
    }
    fgsum = wsumi(fgsum);
    if (lane == 0) { s_wk[wid * 2] = b1; s_wk[wid * 2 + 1] = b2; s_wi[wid] = fgsum; }
    __syncthreads();
    if (tid < 64) {
        unsigned o1 = (tid < 16) ? s_wk[tid * 2] : 0u;
        unsigned o2 = (tid < 16) ? s_wk[tid * 2 + 1] : 0u;
        int fs = (tid < 16) ? s_wi[tid] : 0;
        for (int o = 8; o; o >>= 1) {
            unsigned p1 = __shfl_xor(o1, o, 64);
            unsigned p2 = __shfl_xor(o2, o, 64);
            if (p1 > o1) { o2 = (o1 > p2 ? o1 : p2); o1 = p1; }
            else if (p1 > o2) o2 = p1;
            fs += __shfl_xor(fs, o, 64);
        }
        if (tid == 0) {
            int bg = HWPX - fs;
            if (bg > 0) {
                unsigned key = (unsigned)bg << 15;          // label BIGL -> suffix 0
                if (key > o1) { o2 = o1; o1 = key; }
                else if (key > o2) o2 = key;
            }
            s_k2 = o2;
        }
    }
    __syncthreads();

    unsigned k2 = s_k2;
    bool have2 = (k2 >> 15) != 0;
    int j = BIGL - (int)(k2 & 0x7FFFu);

    // bbox of runner-up: depth<=1 class lookup per pixel
    if (have2) {
        int lc0 = WW, lc1 = -1;
#pragma unroll
        for (int k = 0; k < 16; ++k) {
            bool in;
            if (fgbits & (1u << k)) in = ((L[lb[k]] & 0xFFFF) == j);
            else                    in = (j == BIGL);
            if (in) { int c = col0 + k; lc0 = min(lc0, c); lc1 = max(lc1, c); }
        }
        int lr0 = (lc1 >= 0) ? row : HH;
        int lr1 = (lc1 >= 0) ? row : -1;
        lr0 = wmini(lr0); lr1 = wmaxi(lr1);
        lc0 = wmini(lc0); lc1 = wmaxi(lc1);
        if (lane == 0 && lr1 >= 0) {
            atomicMin(&s_r0, lr0); atomicMax(&s_r1, lr1);
            atomicMin(&s_c0, lc0); atomicMax(&s_c1, lc1);
        }
    }
    __syncthreads();

    // box sum (mask rectangle re-read)
    float bsum = 0.f;
    if (have2) {
        int r0 = s_r0, r1 = s_r1, c0 = s_c0, c1 = s_c1;
        if (row >= r0 && row <= r1) {
            const float4* m4 = (const float4*)(masks + ((size_t)im << 14) + tid * 16);
#pragma unroll
            for (int q = 0; q < 4; ++q) {
                float4 v = m4[q];
                float vv[4] = {v.x, v.y, v.z, v.w};
#pragma unroll
                for (int t = 0; t < 4; ++t) {
                    int c = col0 + q * 4 + t;
                    if (c >= c0 && c <= c1) bsum += vv[t];
                }
            }
        }
    }
    bsum = wsumf(bsum);
    __syncthreads();
    if (lane == 0) s_wsum[wid] = bsum;
    __syncthreads();
    if (tid < 64) {
        float t = (tid < 16) ? s_wsum[tid] : 0.f;
        for (int o = 8; o; o >>= 1) t += __shfl_xor(t, o, 64);
        if (tid == 0) losses[im] = (s_total - t) * (1.0f / 16384.0f);
    }
}

// =============== fallback: R7 single-kernel path (ws too small) ===============
__global__ __launch_bounds__(NT)
void cc_fallback(const float* __restrict__ masks, float* __restrict__ losses) {
    __shared__ int L[HWPX];
    __shared__ unsigned rowbits[HH][4];
    __shared__ int s_bg;
    __shared__ int s_r0, s_r1, s_c0, s_c1;
    __shared__ unsigned s_k2;
    __shared__ unsigned s_wk[32];
    __shared__ float s_wsum[16];
    __shared__ float s_total;

    const int tid = threadIdx.x;
    const int lane = tid & 63;
    const int wid = tid >> 6;
    const float* msk = masks + (size_t)blockIdx.x * HWPX;
    const int base = tid * 16;
    const int row  = base >> 7;
    const int col0 = base & 127;

    float vals[16];
    const float4* m4 = (const float4*)(msk + base);
#pragma unroll
    for (int q = 0; q < 4; ++q) {
        float4 v = m4[q];
        vals[q*4+0]=v.x; vals[q*4+1]=v.y; vals[q*4+2]=v.z; vals[q*4+3]=v.w;
    }
    unsigned fgbits = 0;
    float tsum = 0.f;
    int lab[16];
    {
        int start = -1;
#pragma unroll
        for (int k = 0; k < 16; ++k) {
            tsum += vals[k];
            if (vals[k] > 0.f) {
                fgbits |= 1u << k;
                if (start < 0) start = k;
                lab[k] = base + start;
            } else { start = -1; lab[k] = BIGL; }
        }
    }
    {
        int4* Lv = (int4*)(L + base);
#pragma unroll
        for (int q = 0; q < 4; ++q)
            Lv[q] = make_int4(lab[q*4], lab[q*4+1], lab[q*4+2], lab[q*4+3]);
    }
    unsigned lf = __shfl(fgbits, lane > 0 ? lane - 1 : lane, 64);
    unsigned rf = __shfl(fgbits, lane < 63 ? lane + 1 : lane, 64);
    const unsigned leftbit  = (col0 > 0)   ? ((lf >> 15) & 1u) : 0u;
    const unsigned rightbit = (col0 < 112) ? (rf & 1u)         : 0u;
    unsigned other = __shfl_xor(fgbits, 1, 64);
    if (!(tid & 1)) rowbits[row][(tid >> 1) & 3] = fgbits | (other << 16);

    tsum = wsumf(tsum);
    if (lane == 0) s_wsum[wid] = tsum;
    if (tid == 0) { s_bg = 0; s_r0 = HH; s_r1 = -1; s_c0 = WW; s_c1 = -1; }
    __syncthreads();
    if (tid < 64) {
        float t = (tid < 16) ? s_wsum[tid] : 0.f;
        for (int o = 8; o; o >>= 1) t += __shfl_xor(t, o, 64);
        if (tid == 0) s_total = t;
    }
    if (fgbits) {
        unsigned up = 0;
        if (row > 0) {
            const int wi  = col0 >> 5;
            const int off = col0 & 31;
            unsigned w0 = rowbits[row - 1][wi];
            unsigned w1 = (wi < 3) ? rowbits[row - 1][wi + 1] : 0u;
            unsigned long long uv = ((unsigned long long)w1 << 32) | w0;
            if (off == 16) up = (unsigned)(uv >> 15) & 0x3FFFFu;
            else {
                unsigned lw = (col0 > 0) ? rowbits[row - 1][wi - 1] : 0u;
                up = (unsigned)((uv << 1) | (lw >> 31)) & 0x3FFFFu;
            }
        }
        if ((fgbits & 1u) && leftbit) uni(L, base, base - 1);
        const unsigned ULv = up & 0xFFFFu;
        const unsigned UPv = (up >> 1) & 0xFFFFu;
        const unsigned URv = (up >> 2) & 0xFFFFu;
        const unsigned lFv = ((fgbits << 1) | leftbit) & 0xFFFFu;
        const unsigned rFv = (fgbits >> 1) | (rightbit << 15);
        unsigned m = fgbits & ( (~lFv & (ULv | UPv | URv))
                              | (lFv & ((UPv & ~ULv) | (~rFv & URv & ~UPv))) );
        while (m) {
            int k = __ffs(m) - 1; m &= m - 1;
            int i = base + k;
            unsigned UL = (ULv >> k) & 1u;
            unsigned UP = (UPv >> k) & 1u;
            unsigned UR = (URv >> k) & 1u;
            unsigned lF = (lFv >> k) & 1u;
            unsigned rF = (rFv >> k) & 1u;
            if (!lF) {
                if (UL)        uni(L, i, i - WW - 1);
                if (UP && !UL) uni(L, i, i - WW);
                if (UR && !UP) uni(L, i, i - WW + 1);
            } else {
                if (UP && !UL)        uni(L, i, i - WW);
                if (!rF && UR && !UP) uni(L, i, i - WW + 1);
            }
        }
    }
    __syncthreads();
    int rr[16];
    int firstRoot = INFI;
    {
        int cur = -1;
#pragma unroll
        for (int k = 0; k < 16; ++k) {
            rr[k] = -1;
            if (fgbits & (1u << k)) {
                if (k == 0 || !(fgbits & (1u << (k - 1)))) {
                    cur = findRootF(L, base + k);
                    L[base + k] = cur;
                }
                rr[k] = cur;
                if (firstRoot == INFI) firstRoot = cur;
            }
        }
    }
    __syncthreads();
    {
        const int R0 = wmini(firstRoot);
        int giant = 0, bgc = 0, prev = -1, cnt = 0;
#pragma unroll
        for (int k = 0; k < 16; ++k) {
            if (!(fgbits & (1u << k))) { ++bgc; continue; }
            int r = rr[k];
            if (r == R0) ++giant;
            else if (r == prev) ++cnt;
            else {
                if (cnt) atomicAdd(&L[prev], cnt << 16);
                prev = r; cnt = 1;
            }
        }
        if (cnt) atomicAdd(&L[prev], cnt << 16);
        int g = wsumi(giant);
        if (lane == 0 && R0 != INFI && g) atomicAdd(&L[R0], g << 16);
        int bq = wsumi(bgc);
        if (lane == 0 && bq) atomicAdd(&s_bg, bq);
    }
    __syncthreads();
    int bg = s_bg;
    unsigned b1 = 0, b2 = 0;
    if (tid == 0 && bg > 0) b1 = ((unsigned)bg << 15);
    {
        unsigned m = fgbits & ~(fgbits << 1);
        while (m) {
            int k = __ffs(m) - 1; m &= m - 1;
            int hh = base + k;
            int e = L[hh];
            if ((e & 0xFFFF) == hh && (e >> 16) != 0) {
                unsigned key = ((unsigned)(e >> 16) << 15) | (unsigned)(BIGL - hh);
                if (key > b1) { b2 = b1; b1 = key; }
                else if (key > b2) b2 = key;
            }
        }
    }
    for (int o = 32; o; o >>= 1) {
        unsigned p1 = __shfl_xor(b1, o, 64);
        unsigned p2 = __shfl_xor(b2, o, 64);
        if (p1 > b1) { b2 = (b1 > p2 ? b1 : p2); b1 = p1; }
        else if (p1 > b2) b2 = p1;
    }
    if (lane == 0) { s_wk[wid * 2] = b1; s_wk[wid * 2 + 1] = b2; }
    __syncthreads();
    if (tid < 64) {
        unsigned o1 = (tid < 16) ? s_wk[tid * 2] : 0u;
        unsigned o2 = (tid < 16) ? s_wk[tid * 2 + 1] : 0u;
        for (int o = 8; o; o >>= 1) {
            unsigned p1 = __shfl_xor(o1, o, 64);
            unsigned p2 = __shfl_xor(o2, o, 64);
            if (p1 > o1) { o2 = (o1 > p2 ? o1 : p2); o1 = p1; }
            else if (p1 > o2) o2 = p1;
        }
        if (tid == 0) s_k2 = o2;
    }
    __syncthreads();
    unsigned k2 = s_k2;
    bool have2 = (k2 >> 15) != 0;
    int j = BIGL - (int)(k2 & 0x7FFFu);
    if (have2) {
        int lc0 = WW, lc1 = -1;
#pragma unroll
        for (int k = 0; k < 16; ++k) {
            bool inc = (fgbits & (1u << k)) ? (rr[k] == j) : (j == BIGL);
            if (inc) {
                int c = col0 + k;
                lc0 = min(lc0, c); lc1 = max(lc1, c);
            }
        }
        int lr0 = (lc1 >= 0) ? row : HH;
        int lr1 = (lc1 >= 0) ? row : -1;
        lr0 = wmini(lr0); lr1 = wmaxi(lr1);
        lc0 = wmini(lc0); lc1 = wmaxi(lc1);
        if (lane == 0 && lr1 >= 0) {
            atomicMin(&s_r0, lr0); atomicMax(&s_r1, lr1);
            atomicMin(&s_c0, lc0); atomicMax(&s_c1, lc1);
        }
    }
    __syncthreads();
    float bsum = 0.f;
    if (have2) {
        int r0 = s_r0, r1 = s_r1, c0 = s_c0, c1 = s_c1;
        if (row >= r0 && row <= r1) {
#pragma unroll
            for (int k = 0; k < 16; ++k) {
                int c = col0 + k;
                if (c >= c0 && c <= c1) bsum += vals[k];
            }
        }
    }
    bsum = wsumf(bsum);
    __syncthreads();
    if (lane == 0) s_wsum[wid] = bsum;
    __syncthreads();
    if (tid < 64) {
        float t = (tid < 16) ? s_wsum[tid] : 0.f;
        for (int o = 8; o; o >>= 1) t += __shfl_xor(t, o, 64);
        if (tid == 0) losses[blockIdx.x] = (s_total - t) * (1.0f / 16384.0f);
    }
}

__global__ void reduce_kernel(const float* __restrict__ losses, float* __restrict__ out, int n) {
    __shared__ float s[4];
    int t = threadIdx.x;                      // 256 threads
    float v = 0.f;
    for (int i = t; i < n; i += 256) v += losses[i];
    for (int off = 32; off; off >>= 1) v += __shfl_down(v, off, 64);
    if ((t & 63) == 0) s[t >> 6] = v;
    __syncthreads();
    if (t == 0) out[0] = (s[0] + s[1] + s[2] + s[3]) / (float)n;
}

extern "C" void kernel_launch(void* const* d_in, const int* in_sizes, int n_in,
                              void* d_out, int out_size, void* d_ws, size_t ws_size,
                              hipStream_t stream) {
    const float* masks = (const float*)d_in[0];
    float* out = (float*)d_out;
    int nmask = in_sizes[0] / HWPX;          // 128
    char* w = (char*)d_ws;
    size_t labsB = (size_t)nmask * HWPX * 2;          // 4 MB  u16 labels
    size_t recsB = (size_t)nmask * 8 * 512 * 4;       // 2 MB  records
    size_t cntB  = (size_t)nmask * 8 * 4;             // counts
    size_t sumB  = (size_t)nmask * 8 * 4;             // per-strip sums
    size_t lossB = (size_t)nmask * 4;
    size_t need = labsB + recsB + cntB + sumB + lossB;
    if (ws_size >= need) {
        unsigned* labs32 = (unsigned*)w;
        unsigned* recs   = (unsigned*)(w + labsB);
        int*      counts = (int*)(w + labsB + recsB);
        float*    sums   = (float*)(w + labsB + recsB + cntB);
        float*    losses = (float*)(w + labsB + recsB + cntB + sumB);
        cc_strip_kernel<<<nmask * 8, NT, 0, stream>>>(masks, labs32, recs, counts, sums);
        cc_stats2<<<nmask, NT, 0, stream>>>(masks, labs32, recs, counts, sums, losses);
        reduce_kernel<<<1, 256, 0, stream>>>(losses, out, nmask);
    } else {
        float* losses = (float*)d_ws;
        cc_fallback<<<nmask, NT, 0, stream>>>(masks, losses);
        reduce_kernel<<<1, 256, 0, stream>>>(losses, out, nmask);
    }
}

// Round 11
// 47.154 us; speedup vs baseline: 1.6703x; 1.6703x over previous
//
#include <hip/hip_runtime.h>
#include <hip/hip_bf16.h>
#include <stdint.h>

#define HH 128
#define WW 128
#define HWPX 16384
#define BIGL 16384           // background sentinel
#define NT 1024
#define PPT 16               // contiguous pixels per thread (one 16-col row chunk)

// find with path-halving via atomicMin (monotone decrease -> acyclic, safe
// under concurrent unions; R4-validated fastest variant)
__device__ __forceinline__ int findRootH(int* L, int x) {
    int p = L[x];
    while (p != x) {
        int g = L[p];
        if (g != p) atomicMin(&L[x], g);
        x = p; p = g;
    }
    return x;
}
// post-merge find with plain-store halving (no concurrent unions)
__device__ __forceinline__ int findRootF(int* L, int x) {
    int p = L[x];
    while (p != x) {
        int g = L[p];
        if (g != p) L[x] = g;
        x = p; p = g;
    }
    return p;
}
// ECL-CC style hook: on a failed atomicMin, continue from the returned
// pointer instead of re-finding the root (saves a dependent LDS chase per
// retry; values only decrease -> acyclic, same correctness argument).
__device__ __forceinline__ void uni(int* L, int a, int b) {
    a = findRootH(L, a);
    b = findRootH(L, b);
    while (a != b) {
        if (a > b) { int t = a; a = b; b = t; }   // a < b: link b -> a
        int old = atomicMin(&L[b], a);
        if (old == b) break;                      // linked
        b = old;                                  // splice: walk down, retry
    }
}

__device__ __forceinline__ int wsumi(int v)    { for (int o = 32; o; o >>= 1) v += __shfl_xor(v, o, 64); return v; }
__device__ __forceinline__ float wsumf(float v){ for (int o = 32; o; o >>= 1) v += __shfl_xor(v, o, 64); return v; }
__device__ __forceinline__ int wmini(int v)    { for (int o = 32; o; o >>= 1) v = min(v, __shfl_xor(v, o, 64)); return v; }
__device__ __forceinline__ int wmaxi(int v)    { for (int o = 32; o; o >>= 1) v = max(v, __shfl_xor(v, o, 64)); return v; }

__global__ __launch_bounds__(NT)
void cc_kernel(const float* __restrict__ masks, float* __restrict__ losses) {
    __shared__ int L[HWPX];              // 64 KB: UF parent; roots get area<<16
    __shared__ unsigned rowbits[HH][4];  // 2 KB: fg bitmap
    __shared__ int s_bg;
    __shared__ int s_r0, s_r1, s_c0, s_c1;
    __shared__ unsigned s_k2;
    __shared__ unsigned s_wk[32];
    __shared__ float s_wsum[16];
    __shared__ float s_total;

    const int tid = threadIdx.x;
    const int lane = tid & 63;
    const int wid = tid >> 6;
    const float* msk = masks + (size_t)blockIdx.x * HWPX;
    const int base = tid * PPT;
    const int row  = base >> 7;
    const int col0 = base & 127;

    // ---- vectorized load, fg detect, total sum, run-head labels in regs ----
    float vals[PPT];
    const float4* m4 = (const float4*)(msk + base);
#pragma unroll
    for (int q = 0; q < 4; ++q) {
        float4 v = m4[q];
        vals[q * 4 + 0] = v.x; vals[q * 4 + 1] = v.y;
        vals[q * 4 + 2] = v.z; vals[q * 4 + 3] = v.w;
    }
    unsigned fgbits = 0;
    float tsum = 0.f;
    int lab[PPT];
    {
        int start = -1;
#pragma unroll
        for (int k = 0; k < PPT; ++k) {
            tsum += vals[k];
            if (vals[k] > 0.f) {
                fgbits |= 1u << k;
                if (start < 0) start = k;
                lab[k] = base + start;
            } else {
                start = -1;
                lab[k] = BIGL;
            }
        }
    }
    // vectorized label init: 4x ds_write_b128
    {
        int4* Lv = (int4*)(L + base);
#pragma unroll
        for (int q = 0; q < 4; ++q)
            Lv[q] = make_int4(lab[q * 4], lab[q * 4 + 1], lab[q * 4 + 2], lab[q * 4 + 3]);
    }
    unsigned lf = __shfl(fgbits, lane > 0 ? lane - 1 : lane, 64);
    unsigned rf = __shfl(fgbits, lane < 63 ? lane + 1 : lane, 64);
    const unsigned leftbit  = (col0 > 0)   ? ((lf >> 15) & 1u) : 0u;
    const unsigned rightbit = (col0 < 112) ? (rf & 1u)         : 0u;
    unsigned other = __shfl_xor(fgbits, 1, 64);
    if (!(tid & 1)) rowbits[row][(tid >> 1) & 3] = fgbits | (other << 16);

    tsum = wsumf(tsum);
    if (lane == 0) s_wsum[wid] = tsum;
    if (tid == 0) { s_bg = 0; s_r0 = HH; s_r1 = -1; s_c0 = WW; s_c1 = -1; }
    __syncthreads();

    // ---- wave0: total; all: merge pass (event-masked dedup'd unions) ----
    if (tid < 64) {
        float t = (tid < 16) ? s_wsum[tid] : 0.f;
        for (int o = 8; o; o >>= 1) t += __shfl_xor(t, o, 64);
        if (tid == 0) s_total = t;
    }
    if (fgbits) {
        unsigned up = 0;
        if (row > 0) {
            const int wi  = col0 >> 5;
            const int off = col0 & 31;
            unsigned w0 = rowbits[row - 1][wi];
            unsigned w1 = (wi < 3) ? rowbits[row - 1][wi + 1] : 0u;
            unsigned long long uv = ((unsigned long long)w1 << 32) | w0;
            if (off == 16) {
                up = (unsigned)(uv >> 15) & 0x3FFFFu;
            } else {
                unsigned lw = (col0 > 0) ? rowbits[row - 1][wi - 1] : 0u;
                up = (unsigned)((uv << 1) | (lw >> 31)) & 0x3FFFFu;
            }
        }
        if ((fgbits & 1u) && leftbit) uni(L, base, base - 1);
        // per-pixel neighbor vectors (bit k = that flag for pixel k)
        const unsigned ULv = up & 0xFFFFu;
        const unsigned UPv = (up >> 1) & 0xFFFFu;
        const unsigned URv = (up >> 2) & 0xFFFFu;
        const unsigned lFv = ((fgbits << 1) | leftbit) & 0xFFFFu;
        const unsigned rFv = (fgbits >> 1) | (rightbit << 15);
        // pixels that issue at least one union
        unsigned m = fgbits & ( (~lFv & (ULv | UPv | URv))
                              | (lFv & ((UPv & ~ULv) | (~rFv & URv & ~UPv))) );
        while (m) {
            int k = __ffs(m) - 1; m &= m - 1;
            // own run head via bit trick (no runtime-indexed array -> no scratch):
            // highest bg bit below k (+1) is the run start within this chunk.
            unsigned t = ~fgbits & ((1u << k) - 1u);
            int head = base + (t ? (32 - __builtin_clz(t)) : 0);
            unsigned UL = (ULv >> k) & 1u;
            unsigned UP = (UPv >> k) & 1u;
            unsigned UR = (URv >> k) & 1u;
            unsigned lF = (lFv >> k) & 1u;
            unsigned rF = (rFv >> k) & 1u;
            int i = base + k;
            if (!lF) {
                if (UL)        uni(L, head, i - WW - 1);
                if (UP && !UL) uni(L, head, i - WW);
                if (UR && !UP) uni(L, head, i - WW + 1);
            } else {
                if (UP && !UL)        uni(L, head, i - WW);
                if (!rF && UR && !UP) uni(L, head, i - WW + 1);
            }
        }
    }
    __syncthreads();

    // ---- flatten: one find per run; compress run heads; track first root ----
    int rr[PPT];
    int firstRoot = 0x7FFFFFFF;
    {
        int cur = -1;
#pragma unroll
        for (int k = 0; k < PPT; ++k) {
            rr[k] = -1;
            if (fgbits & (1u << k)) {
                if (k == 0 || !(fgbits & (1u << (k - 1)))) {
                    cur = findRootF(L, base + k);
                    L[base + k] = cur;
                }
                rr[k] = cur;
                if (firstRoot == 0x7FFFFFFF) firstRoot = cur;
            }
        }
    }
    __syncthreads();

    // ---- areas: wave-combined for dominant root, run-length for the rest ----
    {
        const int R0 = wmini(firstRoot);          // wave-uniform hot root
        int giant = 0, bgc = 0, prev = -1, cnt = 0;
#pragma unroll
        for (int k = 0; k < PPT; ++k) {
            if (!(fgbits & (1u << k))) { ++bgc; continue; }
            int r = rr[k];
            if (r == R0) { ++giant; }
            else if (r == prev) ++cnt;
            else {
                if (cnt) atomicAdd(&L[prev], cnt << 16);
                prev = r; cnt = 1;
            }
        }
        if (cnt) atomicAdd(&L[prev], cnt << 16);
        int g = wsumi(giant);
        if (lane == 0 && R0 != 0x7FFFFFFF && g) atomicAdd(&L[R0], g << 16);
        int b = wsumi(bgc);
        if (lane == 0 && b) atomicAdd(&s_bg, b);
    }
    __syncthreads();

    // ---- top-2 by key = (area<<15) | (BIGL - label), scan run heads only ----
    // (a component's root is always a chunk-local run head)
    int bg = s_bg;
    unsigned b1 = 0, b2 = 0;
    if (tid == 0 && bg > 0) b1 = ((unsigned)bg << 15);
    {
        unsigned m = fgbits & ~(fgbits << 1);     // chunk-local run heads
        while (m) {
            int k = __ffs(m) - 1; m &= m - 1;
            int h = base + k;
            int e = L[h];
            if ((e & 0xFFFF) == h && (e >> 16) != 0) {
                unsigned key = ((unsigned)(e >> 16) << 15) | (unsigned)(BIGL - h);
                if (key > b1) { b2 = b1; b1 = key; }
                else if (key > b2) b2 = key;
            }
        }
    }
    for (int o = 32; o; o >>= 1) {
        unsigned p1 = __shfl_xor(b1, o, 64);
        unsigned p2 = __shfl_xor(b2, o, 64);
        if (p1 > b1) { b2 = (b1 > p2 ? b1 : p2); b1 = p1; }
        else if (p1 > b2) b2 = p1;
    }
    if (lane == 0) { s_wk[wid * 2] = b1; s_wk[wid * 2 + 1] = b2; }
    __syncthreads();
    if (tid < 64) {
        unsigned o1 = (tid < 16) ? s_wk[tid * 2] : 0u;
        unsigned o2 = (tid < 16) ? s_wk[tid * 2 + 1] : 0u;
        for (int o = 8; o; o >>= 1) {
            unsigned p1 = __shfl_xor(o1, o, 64);
            unsigned p2 = __shfl_xor(o2, o, 64);
            if (p1 > o1) { o2 = (o1 > p2 ? o1 : p2); o1 = p1; }
            else if (p1 > o2) o2 = p1;
        }
        if (tid == 0) s_k2 = o2;
    }
    __syncthreads();

    unsigned k2 = s_k2;
    bool have2 = (k2 >> 15) != 0;
    int j = BIGL - (int)(k2 & 0x7FFFu);      // runner-up label (BIGL == background)

    // ---- bbox of component j (wave-combined atomics) ----
    if (have2) {
        int lc0 = WW, lc1 = -1;
#pragma unroll
        for (int k = 0; k < PPT; ++k) {
            bool inc = (fgbits & (1u << k)) ? (rr[k] == j) : (j == BIGL);
            if (inc) {
                int c = col0 + k;
                lc0 = min(lc0, c); lc1 = max(lc1, c);
            }
        }
        int lr0 = (lc1 >= 0) ? row : HH;
        int lr1 = (lc1 >= 0) ? row : -1;
        lr0 = wmini(lr0); lr1 = wmaxi(lr1);
        lc0 = wmini(lc0); lc1 = wmaxi(lc1);
        if (lane == 0 && lr1 >= 0) {
            atomicMin(&s_r0, lr0); atomicMax(&s_r1, lr1);
            atomicMin(&s_c0, lc0); atomicMax(&s_c1, lc1);
        }
    }
    __syncthreads();

    // ---- sum inside box (from registers) ----
    float bsum = 0.f;
    if (have2) {
        int r0 = s_r0, r1 = s_r1, c0 = s_c0, c1 = s_c1;
        if (row >= r0 && row <= r1) {
#pragma unroll
            for (int k = 0; k < PPT; ++k) {
                int c = col0 + k;
                if (c >= c0 && c <= c1) bsum += vals[k];
            }
        }
    }
    bsum = wsumf(bsum);
    if (lane == 0) s_wsum[wid] = bsum;   // safe: prior s_wsum readers finished
    __syncthreads();                     // phases ago (barrier-separated)
    if (tid < 64) {
        float t = (tid < 16) ? s_wsum[tid] : 0.f;
        for (int o = 8; o; o >>= 1) t += __shfl_xor(t, o, 64);
        if (tid == 0) losses[blockIdx.x] = (s_total - t) * (1.0f / 16384.0f);
    }
}

__global__ void reduce_kernel(const float* __restrict__ losses, float* __restrict__ out, int n) {
    __shared__ float s[4];
    int t = threadIdx.x;                      // 256 threads
    float v = 0.f;
    for (int i = t; i < n; i += 256) v += losses[i];
    for (int off = 32; off; off >>= 1) v += __shfl_down(v, off, 64);
    if ((t & 63) == 0) s[t >> 6] = v;
    __syncthreads();
    if (t == 0) out[0] = (s[0] + s[1] + s[2] + s[3]) / (float)n;
}

extern "C" void kernel_launch(void* const* d_in, const int* in_sizes, int n_in,
                              void* d_out, int out_size, void* d_ws, size_t ws_size,
                              hipStream_t stream) {
    const float* masks = (const float*)d_in[0];
    float* out = (float*)d_out;
    float* losses = (float*)d_ws;
    int nmask = in_sizes[0] / HWPX;          // 8*16 = 128
    cc_kernel<<<nmask, NT, 0, stream>>>(masks, losses);
    reduce_kernel<<<1, 256, 0, stream>>>(losses, out, nmask);
}